// Round 2
// baseline (783.737 us; speedup 1.0000x reference)
//
#include <hip/hip_runtime.h>
#include <hip/hip_bf16.h>

typedef unsigned short u16;
typedef unsigned int   u32;
typedef __attribute__((ext_vector_type(8))) short short8;
typedef __attribute__((ext_vector_type(4))) float f32x4;
typedef __attribute__((ext_vector_type(4))) u16   u16x4;

#define MFMA16(a,b,c) __builtin_amdgcn_mfma_f32_16x16x32_bf16((a),(b),(c),0,0,0)

#define BATCH 4
#define NPIX  4096     // 64*64
#define CCH   512
#define DDIM  64

static __device__ __forceinline__ u16 f2bf(float f){
  __hip_bfloat16 h = __float2bfloat16(f);
  return __builtin_bit_cast(u16, h);
}
static __device__ __forceinline__ float bf2f(u16 u){
  __hip_bfloat16 h = __builtin_bit_cast(__hip_bfloat16, u);
  return __bfloat162float(h);
}

// ---------------- kernel 1: convert x and Wv to bf16 ----------------
__global__ __launch_bounds__(256) void k_convert(const f32x4* __restrict__ x,
                                                 const f32x4* __restrict__ wv,
                                                 u16x4* __restrict__ xhi,
                                                 u16x4* __restrict__ wvb){
  const int n1 = (BATCH*NPIX*CCH)/4;   // x in float4s
  const int n2 = (CCH*CCH)/4;          // Wv in float4s
  for (int i = blockIdx.x*blockDim.x + threadIdx.x; i < n1+n2; i += gridDim.x*blockDim.x){
    f32x4 v = (i < n1) ? x[i] : wv[i-n1];
    u16x4 o;
    o[0]=f2bf(v[0]); o[1]=f2bf(v[1]); o[2]=f2bf(v[2]); o[3]=f2bf(v[3]);
    if (i < n1) xhi[i] = o; else wvb[i-n1] = o;
  }
}

// ---------------- kernel 2: q,k projection (fp32) + hi/lo split ----------------
__global__ __launch_bounds__(256) void k_qkproj(const float* __restrict__ x,
                                                const float* __restrict__ Wq,
                                                const float* __restrict__ Wk,
                                                u16* __restrict__ qhi, u16* __restrict__ qlo,
                                                u16* __restrict__ khi, u16* __restrict__ klo){
  __shared__ float xs[32][512];    // 64 KB
  const int pix0 = blockIdx.x * 32;
  // stage 32 pixel rows of x (fp32): 16384 floats
  {
    const f32x4* xg = (const f32x4*)(x + (size_t)pix0*CCH);
    f32x4* xsv = (f32x4*)(&xs[0][0]);
    #pragma unroll
    for (int it=0; it<16; ++it) xsv[threadIdx.x + it*256] = xg[threadIdx.x + it*256];
  }
  __syncthreads();
  const int col = threadIdx.x & 127;   // 0..63 -> q, 64..127 -> k  (wave-uniform)
  const int grp = threadIdx.x >> 7;    // pixel half
  const float* W = (col < 64) ? Wq : Wk;
  const int wc = col & 63;
  float acc[16];
  #pragma unroll
  for (int p=0;p<16;++p) acc[p] = 0.f;
  #pragma unroll 4
  for (int c=0;c<512;++c){
    float w = W[c*64 + wc];
    #pragma unroll
    for (int p=0;p<16;++p) acc[p] += xs[grp*16+p][c] * w;
  }
  #pragma unroll
  for (int p=0;p<16;++p){
    int pix = pix0 + grp*16 + p;
    float v = acc[p];
    u16 hi = f2bf(v);
    u16 lo = f2bf(v - bf2f(hi));
    if (col < 64){ qhi[pix*64+wc] = hi; qlo[pix*64+wc] = lo; }
    else         { khi[pix*64+wc] = hi; klo[pix*64+wc] = lo; }
  }
}

// ---------------- kernel 3: v projection (bf16 MFMA), writes V^T ----------------
// V^T layout: [BATCH][CCH][NPIX] bf16
__global__ __launch_bounds__(256) void k_vproj(const u16* __restrict__ xhi,
                                               const u16* __restrict__ wvb,
                                               u16* __restrict__ vT){
  __shared__ u16 As[64][72];      // x tile [pix][k], padded
  __shared__ u16 Bs[64][266];     // Wv tile [k][c], padded for conflict-free strided reads
  const int pix0 = blockIdx.x * 64;
  const int c0   = blockIdx.y * 256;
  const int tid = threadIdx.x;
  const int w = tid >> 6, l = tid & 63;
  const int lg = l >> 4, ll = l & 15;
  f32x4 acc[4][4];
  #pragma unroll
  for (int mf=0;mf<4;++mf)
    #pragma unroll
    for (int nf=0;nf<4;++nf){ f32x4 z = {0.f,0.f,0.f,0.f}; acc[mf][nf] = z; }

  for (int ks=0; ks<8; ++ks){
    __syncthreads();
    // stage A: 64x64 bf16 (16B chunks): 512 chunks of 8 u16
    #pragma unroll
    for (int it=0; it<2; ++it){
      int ch = tid + it*256; int r = ch>>3, c8 = ch&7;
      *(uint4*)(&As[r][c8*8]) = *(const uint4*)(&xhi[(size_t)(pix0+r)*CCH + ks*64 + c8*8]);
    }
    // stage B: 64x256 bf16: 2048 chunks of 8 u16 (32 chunks per row)
    #pragma unroll
    for (int it=0; it<8; ++it){
      int ch = tid + it*256; int r = ch>>5, c32 = ch&31;
      uint4 d = *(const uint4*)(&wvb[(size_t)(ks*64+r)*CCH + c0 + c32*8]);
      u32* dst = (u32*)(&Bs[r][c32*8]);   // row stride 532B: 4B stores
      dst[0]=d.x; dst[1]=d.y; dst[2]=d.z; dst[3]=d.w;
    }
    __syncthreads();
    #pragma unroll
    for (int kc=0;kc<2;++kc){
      short8 a[4];
      #pragma unroll
      for (int mf=0;mf<4;++mf) a[mf] = *(const short8*)(&As[mf*16 + ll][kc*32 + lg*8]);
      #pragma unroll
      for (int nf=0;nf<4;++nf){
        short8 bb;
        int cc = w*64 + nf*16 + ll;
        #pragma unroll
        for (int e=0;e<8;++e) bb[e] = (short)Bs[kc*32 + lg*8 + e][cc];
        #pragma unroll
        for (int mf=0;mf<4;++mf) acc[mf][nf] = MFMA16(a[mf], bb, acc[mf][nf]);
      }
    }
  }
  // epilogue: pack 4 consecutive-pixel bf16 and store to vT[b][c][n]
  #pragma unroll
  for (int mf=0;mf<4;++mf){
    #pragma unroll
    for (int nf=0;nf<4;++nf){
      int pix = pix0 + mf*16 + lg*4;
      int c   = c0 + w*64 + nf*16 + ll;
      u16x4 o;
      #pragma unroll
      for (int r=0;r<4;++r) o[r] = f2bf(acc[mf][nf][r]);
      size_t off = ((size_t)((pix>>12)*CCH + c))*NPIX + (pix & 4095);
      *(u16x4*)(vT + off) = o;
    }
  }
}

// ---------------- kernel 4: flash attention ----------------
// block: (i-tile of 64 rows, batch). 4 waves; wave w owns v-columns [w*128, w*128+128)
__global__ __launch_bounds__(256,1) void k_flash(const u16* __restrict__ qhi, const u16* __restrict__ qlo,
                                                 const u16* __restrict__ khi, const u16* __restrict__ klo,
                                                 const u16* __restrict__ vT,
                                                 const float* __restrict__ gamma_p,
                                                 float* __restrict__ out){
  __shared__ u16 Qh[64][72];
  __shared__ u16 Ql[64][72];
  __shared__ u16 Ps[64][72];
  __shared__ float smax[64][4];
  __shared__ float ssum[64][4];
  const int b   = blockIdx.y;
  const int it0 = blockIdx.x * 64;
  const int tid = threadIdx.x;
  const int w = tid >> 6, l = tid & 63;
  const int lg = l >> 4, ll = l & 15;

  // K fragments (rows = our softmax rows) kept in registers, hi+lo
  short8 kh[4][2], kl[4][2];
  #pragma unroll
  for (int mf=0;mf<4;++mf)
    #pragma unroll
    for (int kc=0;kc<2;++kc){
      size_t a = ((size_t)(b*NPIX + it0 + mf*16 + ll))*DDIM + kc*32 + lg*8;
      kh[mf][kc] = *(const short8*)(khi + a);
      kl[mf][kc] = *(const short8*)(klo + a);
    }

  f32x4 acc[4][8];
  #pragma unroll
  for (int mf=0;mf<4;++mf)
    #pragma unroll
    for (int nf=0;nf<8;++nf){ f32x4 z = {0.f,0.f,0.f,0.f}; acc[mf][nf] = z; }
  float m_run[4][4], l_run[4][4];
  #pragma unroll
  for (int mf=0;mf<4;++mf)
    #pragma unroll
    for (int r=0;r<4;++r){ m_run[mf][r] = -1e30f; l_run[mf][r] = 0.f; }

  const u16* vbase = vT + (size_t)b*CCH*NPIX;

  for (int jt=0; jt<64; ++jt){
    const int j0 = jt*64;
    __syncthreads();   // (A) previous tile's P/Q reads complete
    // stage q tile (hi and lo): 64 rows x 64 d
    #pragma unroll
    for (int it=0; it<2; ++it){
      int ch = tid + it*256; int r = ch>>3, c8 = ch&7;
      size_t ga = ((size_t)(b*NPIX + j0 + r))*DDIM + c8*8;
      *(uint4*)(&Qh[r][c8*8]) = *(const uint4*)(qhi + ga);
      *(uint4*)(&Ql[r][c8*8]) = *(const uint4*)(qlo + ga);
    }
    __syncthreads();   // (B)

    // S = K . Q^T for this wave's 16 j-columns, 3-term hi/lo
    f32x4 s[4];
    #pragma unroll
    for (int mf=0;mf<4;++mf){ f32x4 z = {0.f,0.f,0.f,0.f}; s[mf] = z; }
    #pragma unroll
    for (int kc=0;kc<2;++kc){
      short8 bh = *(const short8*)(&Qh[w*16 + ll][kc*32 + lg*8]);
      short8 bl = *(const short8*)(&Ql[w*16 + ll][kc*32 + lg*8]);
      #pragma unroll
      for (int mf=0;mf<4;++mf){
        s[mf] = MFMA16(kh[mf][kc], bh, s[mf]);
        s[mf] = MFMA16(kh[mf][kc], bl, s[mf]);
        s[mf] = MFMA16(kl[mf][kc], bh, s[mf]);
      }
    }

    // per-row max over this wave's 16 columns
    float pmax[4][4];
    #pragma unroll
    for (int mf=0;mf<4;++mf)
      #pragma unroll
      for (int r=0;r<4;++r){
        float v = s[mf][r];
        v = fmaxf(v, __shfl_xor(v,1));
        v = fmaxf(v, __shfl_xor(v,2));
        v = fmaxf(v, __shfl_xor(v,4));
        v = fmaxf(v, __shfl_xor(v,8));
        pmax[mf][r] = v;
        if (ll == 0) smax[mf*16 + lg*4 + r][w] = v;
      }
    __syncthreads();   // (C)

    // combine 4 wave partials -> tile max; running max + rescale factor
    float mnew[4][4], scl[4][4];
    #pragma unroll
    for (int mf=0;mf<4;++mf)
      #pragma unroll
      for (int r=0;r<4;++r){
        f32x4 t = *(const f32x4*)(&smax[mf*16 + lg*4 + r][0]);
        float tm = fmaxf(fmaxf(t[0],t[1]), fmaxf(t[2],t[3]));
        float mn = fmaxf(m_run[mf][r], tm);
        scl[mf][r]  = __expf(m_run[mf][r] - mn);
        mnew[mf][r] = mn;
      }

    // P = exp(S - m), partial sums, stage P in LDS (bf16)
    #pragma unroll
    for (int mf=0;mf<4;++mf)
      #pragma unroll
      for (int r=0;r<4;++r){
        float p = __expf(s[mf][r] - mnew[mf][r]);
        float ps = p;
        ps += __shfl_xor(ps,1);
        ps += __shfl_xor(ps,2);
        ps += __shfl_xor(ps,4);
        ps += __shfl_xor(ps,8);
        Ps[mf*16 + lg*4 + r][w*16 + ll] = f2bf(p);
        if (ll == 0) ssum[mf*16 + lg*4 + r][w] = ps;
      }
    __syncthreads();   // (D)

    // update l, rescale accumulators
    #pragma unroll
    for (int mf=0;mf<4;++mf)
      #pragma unroll
      for (int r=0;r<4;++r){
        f32x4 t = *(const f32x4*)(&ssum[mf*16 + lg*4 + r][0]);
        float ts = (t[0]+t[1]) + (t[2]+t[3]);
        l_run[mf][r] = l_run[mf][r]*scl[mf][r] + ts;
        m_run[mf][r] = mnew[mf][r];
      }
    #pragma unroll
    for (int mf=0;mf<4;++mf)
      #pragma unroll
      for (int nf=0;nf<8;++nf)
        #pragma unroll
        for (int r=0;r<4;++r) acc[mf][nf][r] *= scl[mf][r];

    // PV: A = P from LDS, B = V^T direct from global
    #pragma unroll
    for (int kc=0;kc<2;++kc){
      short8 pa[4];
      #pragma unroll
      for (int mf=0;mf<4;++mf) pa[mf] = *(const short8*)(&Ps[mf*16 + ll][kc*32 + lg*8]);
      #pragma unroll
      for (int nf=0;nf<8;++nf){
        int c = w*128 + nf*16 + ll;
        short8 vb = *(const short8*)(vbase + (size_t)c*NPIX + j0 + kc*32 + lg*8);
        #pragma unroll
        for (int mf=0;mf<4;++mf) acc[mf][nf] = MFMA16(pa[mf], vb, acc[mf][nf]);
      }
    }
  }

  // epilogue
  const float g = gamma_p[0];
  #pragma unroll
  for (int mf=0;mf<4;++mf)
    #pragma unroll
    for (int nf=0;nf<8;++nf)
      #pragma unroll
      for (int r=0;r<4;++r){
        int row = mf*16 + lg*4 + r;
        int c   = w*128 + nf*16 + ll;
        out[((size_t)(b*NPIX + it0 + row))*CCH + c] = g * acc[mf][nf][r] / l_run[mf][r];
      }
}

extern "C" void kernel_launch(void* const* d_in, const int* in_sizes, int n_in,
                              void* d_out, int out_size, void* d_ws, size_t ws_size,
                              hipStream_t stream) {
  (void)in_sizes; (void)n_in; (void)out_size; (void)ws_size;
  const float* x  = (const float*)d_in[0];
  const float* Wq = (const float*)d_in[1];
  const float* Wk = (const float*)d_in[2];
  const float* Wv = (const float*)d_in[3];
  const float* gm = (const float*)d_in[4];
  float* out = (float*)d_out;

  // persistent scratch in d_ws (24 MB needed)
  u16* qhi = (u16*)d_ws;
  u16* qlo = qhi + (size_t)BATCH*NPIX*DDIM;
  u16* khi = qlo + (size_t)BATCH*NPIX*DDIM;
  u16* klo = khi + (size_t)BATCH*NPIX*DDIM;
  u16* vT  = klo + (size_t)BATCH*NPIX*DDIM;        // [B][C][N], 16 MB

  // transient bf16 copies live INSIDE d_out (33.5 MB); fully consumed by
  // k_vproj before k_flash overwrites d_out with the real output.
  u16* xhi = (u16*)d_out;                          // 16 MB
  u16* wvb = xhi + (size_t)BATCH*NPIX*CCH;         // 0.5 MB

  k_convert<<<dim3(2048), dim3(256), 0, stream>>>((const f32x4*)x, (const f32x4*)Wv,
                                                  (u16x4*)xhi, (u16x4*)wvb);
  k_qkproj<<<dim3(512), dim3(256), 0, stream>>>(x, Wq, Wk, qhi, qlo, khi, klo);
  k_vproj<<<dim3(256,2), dim3(256), 0, stream>>>(xhi, wvb, vT);
  k_flash<<<dim3(64,4), dim3(256), 0, stream>>>(qhi, qlo, khi, klo, vT, gm, out);
}

// Round 3
// 491.553 us; speedup vs baseline: 1.5944x; 1.5944x over previous
//
#include <hip/hip_runtime.h>
#include <hip/hip_bf16.h>

typedef unsigned short u16;
typedef unsigned int   u32;
typedef __attribute__((ext_vector_type(8))) short short8;
typedef __attribute__((ext_vector_type(4))) float f32x4;
typedef __attribute__((ext_vector_type(4))) u16   u16x4;

#define MFMA16(a,b,c) __builtin_amdgcn_mfma_f32_16x16x32_bf16((a),(b),(c),0,0,0)

#define BATCH 4
#define NPIX  4096     // 64*64
#define CCH   512
#define DDIM  64

static __device__ __forceinline__ u16 f2bf(float f){
  __hip_bfloat16 h = __float2bfloat16(f);
  return __builtin_bit_cast(u16, h);
}
static __device__ __forceinline__ float bf2f(u16 u){
  __hip_bfloat16 h = __builtin_bit_cast(__hip_bfloat16, u);
  return __bfloat162float(h);
}

// ---------------- kernel 1: convert x and Wv to bf16 ----------------
__global__ __launch_bounds__(256) void k_convert(const f32x4* __restrict__ x,
                                                 const f32x4* __restrict__ wv,
                                                 u16x4* __restrict__ xhi,
                                                 u16x4* __restrict__ wvb){
  const int n1 = (BATCH*NPIX*CCH)/4;   // x in float4s
  const int n2 = (CCH*CCH)/4;          // Wv in float4s
  for (int i = blockIdx.x*blockDim.x + threadIdx.x; i < n1+n2; i += gridDim.x*blockDim.x){
    f32x4 v = (i < n1) ? x[i] : wv[i-n1];
    u16x4 o;
    o[0]=f2bf(v[0]); o[1]=f2bf(v[1]); o[2]=f2bf(v[2]); o[3]=f2bf(v[3]);
    if (i < n1) xhi[i] = o; else wvb[i-n1] = o;
  }
}

// ---------------- kernel 2: q,k projection (fp32) + hi/lo split ----------------
__global__ __launch_bounds__(256) void k_qkproj(const float* __restrict__ x,
                                                const float* __restrict__ Wq,
                                                const float* __restrict__ Wk,
                                                u16* __restrict__ qhi, u16* __restrict__ qlo,
                                                u16* __restrict__ khi, u16* __restrict__ klo){
  __shared__ float xs[32][512];    // 64 KB
  const int pix0 = blockIdx.x * 32;
  {
    const f32x4* xg = (const f32x4*)(x + (size_t)pix0*CCH);
    f32x4* xsv = (f32x4*)(&xs[0][0]);
    #pragma unroll
    for (int it=0; it<16; ++it) xsv[threadIdx.x + it*256] = xg[threadIdx.x + it*256];
  }
  __syncthreads();
  const int col = threadIdx.x & 127;   // 0..63 -> q, 64..127 -> k  (wave-uniform)
  const int grp = threadIdx.x >> 7;    // pixel half
  const float* W = (col < 64) ? Wq : Wk;
  const int wc = col & 63;
  float acc[16];
  #pragma unroll
  for (int p=0;p<16;++p) acc[p] = 0.f;
  #pragma unroll 4
  for (int c=0;c<512;++c){
    float w = W[c*64 + wc];
    #pragma unroll
    for (int p=0;p<16;++p) acc[p] += xs[grp*16+p][c] * w;
  }
  #pragma unroll
  for (int p=0;p<16;++p){
    int pix = pix0 + grp*16 + p;
    float v = acc[p];
    u16 hi = f2bf(v);
    u16 lo = f2bf(v - bf2f(hi));
    if (col < 64){ qhi[pix*64+wc] = hi; qlo[pix*64+wc] = lo; }
    else         { khi[pix*64+wc] = hi; klo[pix*64+wc] = lo; }
  }
}

// ---------------- kernel 3: v projection (bf16 MFMA), writes V^T ----------------
// V^T layout: [BATCH][CCH][NPIX] bf16
__global__ __launch_bounds__(256) void k_vproj(const u16* __restrict__ xhi,
                                               const u16* __restrict__ wvb,
                                               u16* __restrict__ vT){
  __shared__ u16 As[64][72];      // x tile [pix][k], padded
  __shared__ u16 Bs[64][266];     // Wv tile [k][c], padded
  const int pix0 = blockIdx.x * 64;
  const int c0   = blockIdx.y * 256;
  const int tid = threadIdx.x;
  const int w = tid >> 6, l = tid & 63;
  const int lg = l >> 4, ll = l & 15;
  f32x4 acc[4][4];
  #pragma unroll
  for (int mf=0;mf<4;++mf)
    #pragma unroll
    for (int nf=0;nf<4;++nf){ f32x4 z = {0.f,0.f,0.f,0.f}; acc[mf][nf] = z; }

  for (int ks=0; ks<8; ++ks){
    __syncthreads();
    #pragma unroll
    for (int it=0; it<2; ++it){
      int ch = tid + it*256; int r = ch>>3, c8 = ch&7;
      *(uint4*)(&As[r][c8*8]) = *(const uint4*)(&xhi[(size_t)(pix0+r)*CCH + ks*64 + c8*8]);
    }
    #pragma unroll
    for (int it=0; it<8; ++it){
      int ch = tid + it*256; int r = ch>>5, c32 = ch&31;
      uint4 d = *(const uint4*)(&wvb[(size_t)(ks*64+r)*CCH + c0 + c32*8]);
      u32* dst = (u32*)(&Bs[r][c32*8]);
      dst[0]=d.x; dst[1]=d.y; dst[2]=d.z; dst[3]=d.w;
    }
    __syncthreads();
    #pragma unroll
    for (int kc=0;kc<2;++kc){
      short8 a[4];
      #pragma unroll
      for (int mf=0;mf<4;++mf) a[mf] = *(const short8*)(&As[mf*16 + ll][kc*32 + lg*8]);
      #pragma unroll
      for (int nf=0;nf<4;++nf){
        short8 bb;
        int cc = w*64 + nf*16 + ll;
        #pragma unroll
        for (int e=0;e<8;++e) bb[e] = (short)Bs[kc*32 + lg*8 + e][cc];
        #pragma unroll
        for (int mf=0;mf<4;++mf) acc[mf][nf] = MFMA16(a[mf], bb, acc[mf][nf]);
      }
    }
  }
  #pragma unroll
  for (int mf=0;mf<4;++mf){
    #pragma unroll
    for (int nf=0;nf<4;++nf){
      int pix = pix0 + mf*16 + lg*4;
      int c   = c0 + w*64 + nf*16 + ll;
      u16x4 o;
      #pragma unroll
      for (int r=0;r<4;++r) o[r] = f2bf(acc[mf][nf][r]);
      size_t off = ((size_t)((pix>>12)*CCH + c))*NPIX + (pix & 4095);
      *(u16x4*)(vT + off) = o;
    }
  }
}

// ---------------- kernel 4 v2: flash attention, swapped-S / in-lane softmax ----
// grid (64 itiles, 2 c-halves, 4 batch), 256 threads.
// Block: 64 i-rows x 256 out-cols. Wave wv: softmax rows [i0+wv*16,+16),
// PV cols [c0+wv*64,+64) x all 64 i. One barrier per j-tile.
__global__ __launch_bounds__(256) void k_flash2(const u16* __restrict__ qhi, const u16* __restrict__ qlo,
                                                const u16* __restrict__ khi, const u16* __restrict__ klo,
                                                const u16* __restrict__ vT,
                                                const float* __restrict__ gamma_p,
                                                float* __restrict__ out){
  __shared__ u16  Ps[2][64][72];     // P tile, [i][j] padded, double-buffered
  __shared__ float scl_s[2][64];     // per-row rescale factor
  __shared__ float l_s[64];          // final denominators
  const int b  = blockIdx.z;
  const int i0 = blockIdx.x * 64;
  const int c0 = blockIdx.y * 256;
  const int tid = threadIdx.x;
  const int wv = tid >> 6, l = tid & 63;
  const int lg = l >> 4, ll = l & 15;

  // K B-fragments for this wave's 16 i-rows (hi+lo), kept in regs
  short8 kh[2], kl[2];
  #pragma unroll
  for (int kc=0;kc<2;++kc){
    size_t a = ((size_t)(b*NPIX + i0 + wv*16 + ll))*DDIM + kc*32 + lg*8;
    kh[kc] = *(const short8*)(khi + a);
    kl[kc] = *(const short8*)(klo + a);
  }

  f32x4 acc[4][4];
  #pragma unroll
  for (int mf=0;mf<4;++mf)
    #pragma unroll
    for (int nf=0;nf<4;++nf){ f32x4 z = {0.f,0.f,0.f,0.f}; acc[mf][nf] = z; }
  float m_run = -1e30f, l_run = 0.f;   // for i-col = ll (replicated over lg)

  const u16* vbase = vT  + (size_t)b*CCH*NPIX;
  const u16* qh_b  = qhi + (size_t)b*NPIX*DDIM;
  const u16* ql_b  = qlo + (size_t)b*NPIX*DDIM;

  for (int jt=0; jt<64; ++jt){
    const int j0 = jt*64, buf = jt & 1;

    // ---- S^T = Q . K^T for this wave's 16 i, all 64 j (3-term hi/lo) ----
    f32x4 s[4];
    #pragma unroll
    for (int jf=0;jf<4;++jf){ f32x4 z = {0.f,0.f,0.f,0.f}; s[jf] = z; }
    #pragma unroll
    for (int kc=0;kc<2;++kc){
      #pragma unroll
      for (int jf=0;jf<4;++jf){
        size_t qa = (size_t)(j0 + jf*16 + ll)*DDIM + kc*32 + lg*8;
        short8 qh = *(const short8*)(qh_b + qa);
        short8 ql = *(const short8*)(ql_b + qa);
        s[jf] = MFMA16(qh, kh[kc], s[jf]);
        s[jf] = MFMA16(ql, kh[kc], s[jf]);
        s[jf] = MFMA16(qh, kl[kc], s[jf]);
      }
    }

    // ---- prefetch this tile's V fragments (independent of softmax) ----
    short8 vb[8];
    #pragma unroll
    for (int kc=0;kc<2;++kc)
      #pragma unroll
      for (int nf=0;nf<4;++nf){
        int c = c0 + wv*64 + nf*16 + ll;
        vb[kc*4+nf] = *(const short8*)(vbase + (size_t)c*NPIX + j0 + kc*32 + lg*8);
      }

    // ---- in-lane softmax over 16 j-values + reduce over 4 lane-groups ----
    float mx = fmaxf(fmaxf(fmaxf(s[0][0],s[0][1]),fmaxf(s[0][2],s[0][3])),
                     fmaxf(fmaxf(s[1][0],s[1][1]),fmaxf(s[1][2],s[1][3])));
    mx = fmaxf(mx, fmaxf(fmaxf(fmaxf(s[2][0],s[2][1]),fmaxf(s[2][2],s[2][3])),
                         fmaxf(fmaxf(s[3][0],s[3][1]),fmaxf(s[3][2],s[3][3]))));
    mx = fmaxf(mx, __shfl_xor(mx, 16));
    mx = fmaxf(mx, __shfl_xor(mx, 32));
    float mnew = fmaxf(m_run, mx);
    float sc = __expf(m_run - mnew);
    float p[16], psum = 0.f;
    #pragma unroll
    for (int jf=0;jf<4;++jf)
      #pragma unroll
      for (int r=0;r<4;++r){
        float v = __expf(s[jf][r] - mnew);
        p[jf*4+r] = v; psum += v;
      }
    psum += __shfl_xor(psum, 16);
    psum += __shfl_xor(psum, 32);
    l_run = l_run*sc + psum;
    m_run = mnew;

    // ---- stage P (bf16) + scl ----
    #pragma unroll
    for (int jf=0;jf<4;++jf){
      u16x4 pk;
      #pragma unroll
      for (int r=0;r<4;++r) pk[r] = f2bf(p[jf*4+r]);
      *(u16x4*)(&Ps[buf][wv*16 + ll][jf*16 + lg*4]) = pk;
    }
    if (lg == 0) scl_s[buf][wv*16 + ll] = sc;
    __syncthreads();

    // ---- rescale acc (usually skipped: scl==1 once running max settles) ----
    f32x4 sc4[4];
    #pragma unroll
    for (int mf=0;mf<4;++mf) sc4[mf] = *(const f32x4*)(&scl_s[buf][mf*16 + lg*4]);
    bool need = false;
    #pragma unroll
    for (int mf=0;mf<4;++mf)
      #pragma unroll
      for (int r=0;r<4;++r) need |= (sc4[mf][r] != 1.0f);
    if (__any(need)){
      #pragma unroll
      for (int mf=0;mf<4;++mf)
        #pragma unroll
        for (int nf=0;nf<4;++nf)
          #pragma unroll
          for (int r=0;r<4;++r) acc[mf][nf][r] *= sc4[mf][r];
    }

    // ---- PV: A = P (all 64 i) from LDS, B = prefetched V ----
    #pragma unroll
    for (int kc=0;kc<2;++kc){
      short8 pa[4];
      #pragma unroll
      for (int mf=0;mf<4;++mf) pa[mf] = *(const short8*)(&Ps[buf][mf*16 + ll][kc*32 + lg*8]);
      #pragma unroll
      for (int nf=0;nf<4;++nf)
        #pragma unroll
        for (int mf=0;mf<4;++mf) acc[mf][nf] = MFMA16(pa[mf], vb[kc*4+nf], acc[mf][nf]);
    }
  }

  // ---- epilogue ----
  if (lg == 0) l_s[wv*16 + ll] = l_run;
  __syncthreads();
  const float g = gamma_p[0];
  #pragma unroll
  for (int mf=0;mf<4;++mf){
    f32x4 lv = *(const f32x4*)(&l_s[mf*16 + lg*4]);
    f32x4 inv;
    #pragma unroll
    for (int r=0;r<4;++r) inv[r] = g / lv[r];
    #pragma unroll
    for (int nf=0;nf<4;++nf){
      #pragma unroll
      for (int r=0;r<4;++r){
        int row = mf*16 + lg*4 + r;
        int c   = c0 + wv*64 + nf*16 + ll;
        out[((size_t)(b*NPIX + i0 + row))*CCH + c] = acc[mf][nf][r] * inv[r];
      }
    }
  }
}

extern "C" void kernel_launch(void* const* d_in, const int* in_sizes, int n_in,
                              void* d_out, int out_size, void* d_ws, size_t ws_size,
                              hipStream_t stream) {
  (void)in_sizes; (void)n_in; (void)out_size; (void)ws_size;
  const float* x  = (const float*)d_in[0];
  const float* Wq = (const float*)d_in[1];
  const float* Wk = (const float*)d_in[2];
  const float* Wv = (const float*)d_in[3];
  const float* gm = (const float*)d_in[4];
  float* out = (float*)d_out;

  // persistent scratch in d_ws (24 MB needed)
  u16* qhi = (u16*)d_ws;
  u16* qlo = qhi + (size_t)BATCH*NPIX*DDIM;
  u16* khi = qlo + (size_t)BATCH*NPIX*DDIM;
  u16* klo = khi + (size_t)BATCH*NPIX*DDIM;
  u16* vT  = klo + (size_t)BATCH*NPIX*DDIM;        // [B][C][N], 16 MB

  // transient bf16 copies inside d_out (consumed by k_vproj before k_flash2 writes)
  u16* xhi = (u16*)d_out;                          // 16 MB
  u16* wvb = xhi + (size_t)BATCH*NPIX*CCH;         // 0.5 MB

  k_convert<<<dim3(2048), dim3(256), 0, stream>>>((const f32x4*)x, (const f32x4*)Wv,
                                                  (u16x4*)xhi, (u16x4*)wvb);
  k_qkproj<<<dim3(512), dim3(256), 0, stream>>>(x, Wq, Wk, qhi, qlo, khi, klo);
  k_vproj<<<dim3(256,2), dim3(256), 0, stream>>>(xhi, wvb, vT);
  k_flash2<<<dim3(64,2,4), dim3(256), 0, stream>>>(qhi, qlo, khi, klo, vT, gm, out);
}